// Round 1
// baseline (340.408 us; speedup 1.0000x reference)
//
#include <hip/hip_runtime.h>
#include <hip/hip_bf16.h>
#include <stdint.h>

typedef __bf16 bf16;
typedef __bf16 bf16x8 __attribute__((ext_vector_type(8)));
typedef __bf16 bf16x4 __attribute__((ext_vector_type(4)));
typedef float  f32x4  __attribute__((ext_vector_type(4)));

// async global->LDS, 16B per lane; LDS dest = wave-uniform base + lane*16
__device__ __forceinline__ void load_lds16(const void* g, void* l) {
  __builtin_amdgcn_global_load_lds((const __attribute__((address_space(1))) void*)g,
                                   (__attribute__((address_space(3))) void*)l, 16, 0, 0);
}

// ---------------- convert x: f32 -> bf16, 8 elems/thread ----------------
__global__ __launch_bounds__(256) void f32_to_bf16_k(const float* __restrict__ in,
                                                     bf16* __restrict__ out) {
  int i = (blockIdx.x * 256 + threadIdx.x) * 8;
  float4 a = *(const float4*)(in + i);
  float4 b = *(const float4*)(in + i + 4);
  bf16x8 o;
  o[0] = (bf16)a.x; o[1] = (bf16)a.y; o[2] = (bf16)a.z; o[3] = (bf16)a.w;
  o[4] = (bf16)b.x; o[5] = (bf16)b.y; o[6] = (bf16)b.z; o[7] = (bf16)b.w;
  *(bf16x8*)(out + i) = o;
}

// ------------- transpose + convert: W[K][N] f32 -> WT[N][K] bf16 -------------
__global__ __launch_bounds__(256) void transpose_to_bf16_k(const float* __restrict__ in,
                                                           bf16* __restrict__ out,
                                                           int K, int N) {
  __shared__ __align__(16) bf16 tile[64 * 72];  // pad 8 -> 16B-aligned rows, ~2-way banks
  int n0 = blockIdx.x * 64, k0 = blockIdx.y * 64;
  int t = threadIdx.x;
  int r = t >> 2, cq = (t & 3) * 16;
  const float* src = in + (size_t)(k0 + r) * N + n0 + cq;
#pragma unroll
  for (int j = 0; j < 16; j += 4) {
    float4 v = *(const float4*)(src + j);
    tile[r * 72 + cq + j + 0] = (bf16)v.x;
    tile[r * 72 + cq + j + 1] = (bf16)v.y;
    tile[r * 72 + cq + j + 2] = (bf16)v.z;
    tile[r * 72 + cq + j + 3] = (bf16)v.w;
  }
  __syncthreads();
  bf16x8 r0, r1;
#pragma unroll
  for (int j = 0; j < 8; ++j) r0[j] = tile[(cq + j) * 72 + r];
#pragma unroll
  for (int j = 0; j < 8; ++j) r1[j] = tile[(cq + 8 + j) * 72 + r];
  bf16* dst = out + (size_t)(n0 + r) * K + k0 + cq;
  *(bf16x8*)(dst) = r0;
  *(bf16x8*)(dst + 8) = r1;
}

// ---------------- GEMM: C[M][N] = A[M][K] * BT[N][K]^T + bias ----------------
// 128x128 tile, BK=32, 4 waves (2x2), each wave 64x64 via 4x4 of 16x16x32 MFMA.
// EPI 0: QKV split writer (Q,K -> qk[b*2048+s][2048] bf16; V -> vt[(bh*64+d)*2048+s] bf16)
// EPI 1: f32 out + bias
template <int EPI>
__global__ __launch_bounds__(256) void gemm_bt(const bf16* __restrict__ A,
                                               const bf16* __restrict__ BT,
                                               const float* __restrict__ bias,
                                               float* __restrict__ Cf,
                                               bf16* __restrict__ qk,
                                               bf16* __restrict__ vt,
                                               int M, int N, int K) {
  __shared__ __align__(16) bf16 As[128 * 32];
  __shared__ __align__(16) bf16 Bs[128 * 32];
  const int tid = threadIdx.x;
  const int w = tid >> 6, l = tid & 63;
  const int g = l >> 4, c = l & 15;
  const int wm = w >> 1, wn = w & 1;
  const int brow = blockIdx.y * 128;
  const int bcol = blockIdx.x * 128;
  const int lr = l >> 2;         // 16 rows per 1KB inst
  const int lk = (l & 3) * 8;    // k-elem offset (16B per lane)

  f32x4 acc[4][4];
#pragma unroll
  for (int m = 0; m < 4; ++m)
#pragma unroll
    for (int n = 0; n < 4; ++n) acc[m][n] = f32x4{0.f, 0.f, 0.f, 0.f};

  const int nkt = K >> 5;
  for (int kt = 0; kt < nkt; ++kt) {
    if (kt) __syncthreads();
    const int k0 = kt * 32;
#pragma unroll
    for (int i = 0; i < 2; ++i) {
      int row = (w * 2 + i) * 16 + lr;
      load_lds16(A + (size_t)(brow + row) * K + k0 + lk, &As[(w * 2 + i) * 512]);
      load_lds16(BT + (size_t)(bcol + row) * K + k0 + lk, &Bs[(w * 2 + i) * 512]);
    }
    asm volatile("s_waitcnt vmcnt(0)" ::: "memory");
    __syncthreads();

    bf16x8 af[4], bfr[4];
#pragma unroll
    for (int m = 0; m < 4; ++m) af[m] = *(const bf16x8*)&As[(wm * 64 + m * 16 + c) * 32 + g * 8];
#pragma unroll
    for (int n = 0; n < 4; ++n) bfr[n] = *(const bf16x8*)&Bs[(wn * 64 + n * 16 + c) * 32 + g * 8];
#pragma unroll
    for (int m = 0; m < 4; ++m)
#pragma unroll
      for (int n = 0; n < 4; ++n)
        acc[m][n] = __builtin_amdgcn_mfma_f32_16x16x32_bf16(af[m], bfr[n], acc[m][n], 0, 0, 0);
  }

  // epilogue: C row = g*4 + r, col = c (within each 16x16 frag)
#pragma unroll
  for (int m = 0; m < 4; ++m) {
    int row_l = wm * 64 + m * 16 + g * 4;
#pragma unroll
    for (int n = 0; n < 4; ++n) {
      int col = bcol + wn * 64 + n * 16 + c;
      float bv = bias[col];
      if (EPI == 0) {
        if (bcol < 2048) {  // Q or K part: row-major [8192][2048]
#pragma unroll
          for (int r = 0; r < 4; ++r) {
            int row = brow + row_l + r;
            qk[(size_t)row * 2048 + col] = (bf16)(acc[m][n][r] + bv);
          }
        } else {            // V part: transposed [b][h][d][s]
          int hh = (col - 2048) >> 6, dd = (col - 2048) & 63;
          int row0 = brow + row_l;
          int bb = row0 >> 11, ss = row0 & 2047;
          bf16x4 pk;
#pragma unroll
          for (int r = 0; r < 4; ++r) pk[r] = (bf16)(acc[m][n][r] + bv);
          *(bf16x4*)&vt[((size_t)(bb * 16 + hh) * 64 + dd) * 2048 + ss] = pk;
        }
      } else {
#pragma unroll
        for (int r = 0; r < 4; ++r) {
          int row = brow + row_l + r;
          Cf[(size_t)row * N + col] = acc[m][n][r] + bv;
        }
      }
    }
  }
}

// ---------------- flash attention (causal), one 64-row q-block per CTA ----------------
// 4 waves x 16 q-rows. KV tile 64. K and V^T staged linearly via global_load_lds with
// XOR-swizzled SOURCE addresses (slot ^= row&7) so ds_read_b128 hits the bank floor.
__global__ __launch_bounds__(256) void attn_k(const bf16* __restrict__ qkbuf,
                                              const bf16* __restrict__ vtbuf,
                                              bf16* __restrict__ aout) {
  __shared__ __align__(16) bf16 Ks[64 * 64];       // [kv][d] swizzled
  __shared__ __align__(16) bf16 Vs[64 * 64];       // [d][kv] swizzled
  __shared__ __align__(16) bf16 Ps[4][16 * 72];    // per-wave P tile, padded rows

  const int tid = threadIdx.x;
  const int w = tid >> 6, l = tid & 63;
  const int g = l >> 4, c = l & 15;
  const int bh = blockIdx.y;
  const int b = bh >> 4, h = bh & 15;
  const int qblk = gridDim.x - 1 - blockIdx.x;     // heavy blocks first
  const int q0 = qblk * 64;

  // Q fragment, pre-scaled by 1/sqrt(64)=0.125 (exact exponent shift in bf16)
  const size_t qrow = (size_t)(b * 2048 + q0 + w * 16 + c) * 2048 + h * 64;
  bf16x8 qf[2];
#pragma unroll
  for (int kk = 0; kk < 2; ++kk) {
    bf16x8 v = *(const bf16x8*)&qkbuf[qrow + kk * 32 + g * 8];
#pragma unroll
    for (int j = 0; j < 8; ++j) v[j] = (bf16)((float)v[j] * 0.125f);
    qf[kk] = v;
  }

  const int li8 = l >> 3, lm8 = l & 7;
  const int swz = (lm8 ^ li8) * 8;   // source-side swizzle: slot lm8 holds group lm8^row

  float m_r[4], l_r[4];
  f32x4 o[4];
#pragma unroll
  for (int r = 0; r < 4; ++r) { m_r[r] = -1e30f; l_r[r] = 0.f; }
#pragma unroll
  for (int n = 0; n < 4; ++n) o[n] = f32x4{0.f, 0.f, 0.f, 0.f};

  for (int kvt = 0; kvt <= qblk; ++kvt) {
    const int kv0 = kvt * 64;
    __syncthreads();
#pragma unroll
    for (int i = 0; i < 2; ++i) {
      int row = (w * 2 + i) * 8 + li8;   // kv row (K) / d row (V)
      load_lds16(qkbuf + (size_t)(b * 2048 + kv0 + row) * 2048 + 1024 + h * 64 + swz,
                 &Ks[(w * 2 + i) * 512]);
      load_lds16(vtbuf + ((size_t)(bh * 64) + row) * 2048 + kv0 + swz,
                 &Vs[(w * 2 + i) * 512]);
    }
    asm volatile("s_waitcnt vmcnt(0)" ::: "memory");
    __syncthreads();

    // S = Q K^T  (16q x 64kv per wave)
    f32x4 s[4];
#pragma unroll
    for (int n = 0; n < 4; ++n) s[n] = f32x4{0.f, 0.f, 0.f, 0.f};
#pragma unroll
    for (int kk = 0; kk < 2; ++kk) {
#pragma unroll
      for (int n = 0; n < 4; ++n) {
        bf16x8 kf = *(const bf16x8*)&Ks[(n * 16 + c) * 64 + (((kk * 4 + g) ^ (c & 7)) * 8)];
        s[n] = __builtin_amdgcn_mfma_f32_16x16x32_bf16(qf[kk], kf, s[n], 0, 0, 0);
      }
    }

    if (kvt == qblk) {  // diagonal tile: causal mask (kv > q)
#pragma unroll
      for (int n = 0; n < 4; ++n)
#pragma unroll
        for (int r = 0; r < 4; ++r) {
          int qoff = w * 16 + g * 4 + r;
          int kvoff = c + 16 * n;
          if (kvoff > qoff) s[n][r] = -1e30f;
        }
    }

    // online softmax: reduce across the 16 lanes of each l>>4 group (masks 1,2,4,8)
    float al[4];
#pragma unroll
    for (int r = 0; r < 4; ++r) {
      float v = fmaxf(fmaxf(s[0][r], s[1][r]), fmaxf(s[2][r], s[3][r]));
      v = fmaxf(v, __shfl_xor(v, 1, 64));
      v = fmaxf(v, __shfl_xor(v, 2, 64));
      v = fmaxf(v, __shfl_xor(v, 4, 64));
      v = fmaxf(v, __shfl_xor(v, 8, 64));
      float mn = fmaxf(m_r[r], v);
      al[r] = __expf(m_r[r] - mn);
      m_r[r] = mn;
    }
    float ps[4] = {0.f, 0.f, 0.f, 0.f};
#pragma unroll
    for (int n = 0; n < 4; ++n)
#pragma unroll
      for (int r = 0; r < 4; ++r) {
        float p = __expf(s[n][r] - m_r[r]);
        ps[r] += p;
        Ps[w][(g * 4 + r) * 72 + c + 16 * n] = (bf16)p;
      }
#pragma unroll
    for (int r = 0; r < 4; ++r) {
      float v = ps[r];
      v += __shfl_xor(v, 1, 64);
      v += __shfl_xor(v, 2, 64);
      v += __shfl_xor(v, 4, 64);
      v += __shfl_xor(v, 8, 64);
      l_r[r] = l_r[r] * al[r] + v;
#pragma unroll
      for (int n = 0; n < 4; ++n) o[n][r] *= al[r];
    }

    // O += P V   (A = P from LDS, B = V^T rows, kv-contiguous)
#pragma unroll
    for (int kk = 0; kk < 2; ++kk) {
      bf16x8 pf = *(const bf16x8*)&Ps[w][c * 72 + kk * 32 + g * 8];
#pragma unroll
      for (int n = 0; n < 4; ++n) {
        bf16x8 vf = *(const bf16x8*)&Vs[(c + 16 * n) * 64 + (((kk * 4 + g) ^ (c & 7)) * 8)];
        o[n] = __builtin_amdgcn_mfma_f32_16x16x32_bf16(pf, vf, o[n], 0, 0, 0);
      }
    }
  }

#pragma unroll
  for (int n = 0; n < 4; ++n)
#pragma unroll
    for (int r = 0; r < 4; ++r) {
      int q = q0 + w * 16 + g * 4 + r;
      aout[(size_t)(b * 2048 + q) * 1024 + h * 64 + c + 16 * n] = (bf16)(o[n][r] / l_r[r]);
    }
}

// ---------------- launch ----------------
extern "C" void kernel_launch(void* const* d_in, const int* in_sizes, int n_in,
                              void* d_out, int out_size, void* d_ws, size_t ws_size,
                              hipStream_t stream) {
  const float* x    = (const float*)d_in[0];
  const float* Wqkv = (const float*)d_in[1];
  const float* bqkv = (const float*)d_in[2];
  const float* Wo   = (const float*)d_in[3];
  const float* bo   = (const float*)d_in[4];
  float* out = (float*)d_out;

  char* ws = (char*)d_ws;
  bf16* xb   = (bf16*)(ws);                  // 16 MB   [8192][1024]
  bf16* wqt  = (bf16*)(ws + 16777216);       // 6 MB    [3072][1024]
  bf16* wot  = (bf16*)(ws + 23068672);       // 2 MB    [1024][1024]
  bf16* qkb  = (bf16*)(ws + 25165824);       // 32 MB   [8192][2048]  (Q | K)
  bf16* vtb  = (bf16*)(ws + 58720256);       // 16 MB   [64 bh][64 d][2048 s]
  bf16* aob  = (bf16*)(ws + 75497472);       // 16 MB   [8192][1024]

  f32_to_bf16_k<<<dim3(4096), dim3(256), 0, stream>>>(x, xb);
  transpose_to_bf16_k<<<dim3(48, 16), dim3(256), 0, stream>>>(Wqkv, wqt, 1024, 3072);
  transpose_to_bf16_k<<<dim3(16, 16), dim3(256), 0, stream>>>(Wo, wot, 1024, 1024);
  gemm_bt<0><<<dim3(24, 64), dim3(256), 0, stream>>>(xb, wqt, bqkv, nullptr, qkb, vtb,
                                                     8192, 3072, 1024);
  attn_k<<<dim3(32, 64), dim3(256), 0, stream>>>(qkb, vtb, aob);
  gemm_bt<1><<<dim3(8, 64), dim3(256), 0, stream>>>(aob, wot, bo, out, nullptr, nullptr,
                                                    8192, 1024, 1024);
}

// Round 3
// 229.968 us; speedup vs baseline: 1.4802x; 1.4802x over previous
//
#include <hip/hip_runtime.h>
#include <hip/hip_bf16.h>
#include <stdint.h>

typedef __bf16 bf16;
typedef __bf16 bf16x8 __attribute__((ext_vector_type(8)));
typedef __bf16 bf16x4 __attribute__((ext_vector_type(4)));
typedef float  f32x4  __attribute__((ext_vector_type(4)));
typedef float  f32x16 __attribute__((ext_vector_type(16)));

// async global->LDS, 16B per lane; LDS dest = wave-uniform base + lane*16
__device__ __forceinline__ void load_lds16(const void* g, void* l) {
  __builtin_amdgcn_global_load_lds((const __attribute__((address_space(1))) void*)g,
                                   (__attribute__((address_space(3))) void*)l, 16, 0, 0);
}

__device__ __forceinline__ unsigned pk2(float a, float b) {
  union { bf16 h[2]; unsigned u; } t;
  t.h[0] = (bf16)a; t.h[1] = (bf16)b;
  return t.u;
}

// ---------------- convert x: f32 -> bf16, 8 elems/thread ----------------
__global__ __launch_bounds__(256) void f32_to_bf16_k(const float* __restrict__ in,
                                                     bf16* __restrict__ out) {
  int i = (blockIdx.x * 256 + threadIdx.x) * 8;
  float4 a = *(const float4*)(in + i);
  float4 b = *(const float4*)(in + i + 4);
  bf16x8 o;
  o[0] = (bf16)a.x; o[1] = (bf16)a.y; o[2] = (bf16)a.z; o[3] = (bf16)a.w;
  o[4] = (bf16)b.x; o[5] = (bf16)b.y; o[6] = (bf16)b.z; o[7] = (bf16)b.w;
  *(bf16x8*)(out + i) = o;
}

// ------------- transpose + convert: W[K][N] f32 -> WT[N][K] bf16 -------------
__global__ __launch_bounds__(256) void transpose_to_bf16_k(const float* __restrict__ in,
                                                           bf16* __restrict__ out,
                                                           int K, int N) {
  __shared__ __align__(16) bf16 tile[64 * 72];
  int n0 = blockIdx.x * 64, k0 = blockIdx.y * 64;
  int t = threadIdx.x;
  int r = t >> 2, cq = (t & 3) * 16;
  const float* src = in + (size_t)(k0 + r) * N + n0 + cq;
#pragma unroll
  for (int j = 0; j < 16; j += 4) {
    float4 v = *(const float4*)(src + j);
    tile[r * 72 + cq + j + 0] = (bf16)v.x;
    tile[r * 72 + cq + j + 1] = (bf16)v.y;
    tile[r * 72 + cq + j + 2] = (bf16)v.z;
    tile[r * 72 + cq + j + 3] = (bf16)v.w;
  }
  __syncthreads();
  bf16x8 r0, r1;
#pragma unroll
  for (int j = 0; j < 8; ++j) r0[j] = tile[(cq + j) * 72 + r];
#pragma unroll
  for (int j = 0; j < 8; ++j) r1[j] = tile[(cq + 8 + j) * 72 + r];
  bf16* dst = out + (size_t)(n0 + r) * K + k0 + cq;
  *(bf16x8*)(dst) = r0;
  *(bf16x8*)(dst + 8) = r1;
}

// ---------------- GEMM: C[M][N] = A[M][K] * BT[N][K]^T + bias ----------------
template <int EPI>
__global__ __launch_bounds__(256) void gemm_bt(const bf16* __restrict__ A,
                                               const bf16* __restrict__ BT,
                                               const float* __restrict__ bias,
                                               float* __restrict__ Cf,
                                               bf16* __restrict__ qk,
                                               bf16* __restrict__ vt,
                                               int M, int N, int K) {
  __shared__ __align__(16) bf16 As[128 * 32];
  __shared__ __align__(16) bf16 Bs[128 * 32];
  const int tid = threadIdx.x;
  const int w = tid >> 6, l = tid & 63;
  const int g = l >> 4, c = l & 15;
  const int wm = w >> 1, wn = w & 1;
  const int brow = blockIdx.y * 128;
  const int bcol = blockIdx.x * 128;
  const int lr = l >> 2;
  const int lk = (l & 3) * 8;

  f32x4 acc[4][4];
#pragma unroll
  for (int m = 0; m < 4; ++m)
#pragma unroll
    for (int n = 0; n < 4; ++n) acc[m][n] = f32x4{0.f, 0.f, 0.f, 0.f};

  const int nkt = K >> 5;
  for (int kt = 0; kt < nkt; ++kt) {
    if (kt) __syncthreads();
    const int k0 = kt * 32;
#pragma unroll
    for (int i = 0; i < 2; ++i) {
      int row = (w * 2 + i) * 16 + lr;
      load_lds16(A + (size_t)(brow + row) * K + k0 + lk, &As[(w * 2 + i) * 512]);
      load_lds16(BT + (size_t)(bcol + row) * K + k0 + lk, &Bs[(w * 2 + i) * 512]);
    }
    asm volatile("s_waitcnt vmcnt(0)" ::: "memory");
    __syncthreads();

    bf16x8 af[4], bfr[4];
#pragma unroll
    for (int m = 0; m < 4; ++m) af[m] = *(const bf16x8*)&As[(wm * 64 + m * 16 + c) * 32 + g * 8];
#pragma unroll
    for (int n = 0; n < 4; ++n) bfr[n] = *(const bf16x8*)&Bs[(wn * 64 + n * 16 + c) * 32 + g * 8];
#pragma unroll
    for (int m = 0; m < 4; ++m)
#pragma unroll
      for (int n = 0; n < 4; ++n)
        acc[m][n] = __builtin_amdgcn_mfma_f32_16x16x32_bf16(af[m], bfr[n], acc[m][n], 0, 0, 0);
  }

#pragma unroll
  for (int m = 0; m < 4; ++m) {
    int row_l = wm * 64 + m * 16 + g * 4;
#pragma unroll
    for (int n = 0; n < 4; ++n) {
      int col = bcol + wn * 64 + n * 16 + c;
      float bv = bias[col];
      if (EPI == 0) {
        if (bcol < 2048) {
#pragma unroll
          for (int r = 0; r < 4; ++r) {
            int row = brow + row_l + r;
            qk[(size_t)row * 2048 + col] = (bf16)(acc[m][n][r] + bv);
          }
        } else {
          int hh = (col - 2048) >> 6, dd = (col - 2048) & 63;
          int row0 = brow + row_l;
          int bb = row0 >> 11, ss = row0 & 2047;
          bf16x4 pk;
#pragma unroll
          for (int r = 0; r < 4; ++r) pk[r] = (bf16)(acc[m][n][r] + bv);
          *(bf16x4*)&vt[((size_t)(bb * 16 + hh) * 64 + dd) * 2048 + ss] = pk;
        }
      } else {
#pragma unroll
        for (int r = 0; r < 4; ++r) {
          int row = brow + row_l + r;
          Cf[(size_t)row * N + col] = acc[m][n][r] + bv;
        }
      }
    }
  }
}

// ---------------- flash attention v2: swapped-QK^T, in-register softmax ----------------
// 4 waves x 32 q-rows (128 q/block). KVBLK=64, double-buffered K/V^T in LDS
// (XOR-swizzled). S^T = mfma32x32x16(K,Q): lane holds P[kv 0..63] for one q
// (32 local + 32 in lane^32). Softmax: local reg-tree + 1 shfl. P->B-operand
// via bf16 pack + shfl_xor(32) (m214 recipe). No P LDS round-trip.
__global__ __launch_bounds__(256) void attn_k(const bf16* __restrict__ qkbuf,
                                              const bf16* __restrict__ vtbuf,
                                              bf16* __restrict__ aout) {
  __shared__ __align__(16) bf16 Ks[2][64 * 64];
  __shared__ __align__(16) bf16 Vs[2][64 * 64];

  const int tid = threadIdx.x;
  const int w = tid >> 6, l = tid & 63;
  const int c32 = l & 31, hi = l >> 5;

  // XCD-bijective swizzle: 1024 blocks, XCD k gets bh [8k, 8k+8) (4MB K+V -> L2-fit)
  const int bid = blockIdx.x;
  const int swz = ((bid & 7) << 7) + (bid >> 3);
  const int bh = swz >> 4;
  const int qblk = 15 - (swz & 15);     // heavy-first within each XCD chunk
  const int b = bh >> 4, h = bh & 15;
  const int q0 = qblk * 128;
  const int nt = 2 * qblk + 2;          // kv tiles (64 each) to cover q0+128
  const int qw = q0 + w * 32;           // wave's first q row
  const int qmaxw = qw + 31;
  const int myq = qw + c32;             // this lane's q row (same for l and l^32)

  // Q B-fragments: lane holds col q=myq, k(d) = 16t + hi*8 + j. Pre-scaled 1/8.
  const size_t qoff = (size_t)(b * 2048 + myq) * 2048 + h * 64;
  bf16x8 qf[4];
#pragma unroll
  for (int t = 0; t < 4; ++t) {
    bf16x8 v = *(const bf16x8*)&qkbuf[qoff + t * 16 + hi * 8];
#pragma unroll
    for (int j = 0; j < 8; ++j) v[j] = (bf16)((float)v[j] * 0.125f);
    qf[t] = v;
  }

  const bf16* ksrc = qkbuf + (size_t)(b * 2048) * 2048 + 1024 + h * 64;  // K rows
  const bf16* vsrc = vtbuf + (size_t)(bh * 64) * 2048;                   // V^T rows

  float m_r = -1e30f, l_r = 0.f;
  f32x16 o[2];
  o[0] = (f32x16)(0.f); o[1] = (f32x16)(0.f);

  // prologue: stage tile 0 into buf 0
  {
    const int r = w * 16 + (l >> 3);
#pragma unroll
    for (int i = 0; i < 2; ++i) {
      int rr = r + i * 8;
      load_lds16(ksrc + (size_t)rr * 2048 + ((l & 7) ^ (rr & 7)) * 8, &Ks[0][(w * 16 + i * 8) * 64]);
      load_lds16(vsrc + (size_t)rr * 2048 + ((l & 7) ^ (rr & 7)) * 8, &Vs[0][(w * 16 + i * 8) * 64]);
    }
  }
  asm volatile("s_waitcnt vmcnt(0)" ::: "memory");
  __syncthreads();

  int cur = 0;
  for (int kt = 0; kt < nt; ++kt) {
    const int kv0 = kt * 64;

    // stage next tile into the other buffer (its readers barrier'd out last iter)
    if (kt + 1 < nt) {
      const int kvn = (kt + 1) * 64;
      const int r = w * 16 + (l >> 3);
#pragma unroll
      for (int i = 0; i < 2; ++i) {
        int rr = r + i * 8;
        load_lds16(ksrc + (size_t)(kvn + rr) * 2048 + ((l & 7) ^ (rr & 7)) * 8,
                   &Ks[cur ^ 1][(w * 16 + i * 8) * 64]);
        load_lds16(vsrc + (size_t)rr * 2048 + kvn + ((l & 7) ^ (rr & 7)) * 8,
                   &Vs[cur ^ 1][(w * 16 + i * 8) * 64]);
      }
    }

    if (kv0 <= qmaxw) {  // skip tiles fully above this wave's diagonal
      const bf16* kb = &Ks[cur][0];
      const bf16* vb = &Vs[cur][0];

      // S^T[kv][q] accumulate over d: 2 kv-subtiles x 4 ksteps
      f32x16 st[2];
      st[0] = (f32x16)(0.f); st[1] = (f32x16)(0.f);
      __builtin_amdgcn_s_setprio(1);
#pragma unroll
      for (int t = 0; t < 4; ++t) {
#pragma unroll
        for (int ks = 0; ks < 2; ++ks) {
          int kv = ks * 32 + c32;
          bf16x8 kf = *(const bf16x8*)&kb[kv * 64 + (((2 * t + hi) ^ (kv & 7)) * 8)];
          st[ks] = __builtin_amdgcn_mfma_f32_32x32x16_bf16(kf, qf[t], st[ks], 0, 0, 0);
        }
      }
      __builtin_amdgcn_s_setprio(0);

      // causal mask on tiles that reach this wave's diagonal.
      // FIX(R3): mask needed when max kv (kv0+63) exceeds the wave's MIN q row
      // (qw), not its max (qmaxw) — waves 1/3 had unmasked diagonal tiles.
      if (kv0 + 63 > qw) {
#pragma unroll
        for (int ks = 0; ks < 2; ++ks)
#pragma unroll
          for (int r = 0; r < 16; ++r) {
            int kvidx = kv0 + ks * 32 + (r & 3) + 8 * (r >> 2) + 4 * hi;
            if (kvidx > myq) st[ks][r] = -1e30f;
          }
      }

      // online softmax fully in-register: local 32-reg tree + 1 shfl (lane^32)
      float mx = st[0][0];
#pragma unroll
      for (int ks = 0; ks < 2; ++ks)
#pragma unroll
        for (int r = 0; r < 16; ++r) mx = fmaxf(mx, st[ks][r]);
      mx = fmaxf(mx, __shfl_xor(mx, 32, 64));
      float mn = fmaxf(m_r, mx);
      float al = __expf(m_r - mn);
      m_r = mn;
      float ps = 0.f;
#pragma unroll
      for (int ks = 0; ks < 2; ++ks)
#pragma unroll
        for (int r = 0; r < 16; ++r) {
          float p = __expf(st[ks][r] - mn);
          st[ks][r] = p;
          ps += p;
        }
      ps += __shfl_xor(ps, 32, 64);
      l_r = l_r * al + ps;
#pragma unroll
      for (int ds = 0; ds < 2; ++ds)
#pragma unroll
        for (int r = 0; r < 16; ++r) o[ds][r] *= al;

      // P -> bf16 B-operand fragments: per kstep, 4 packs + 2 shfl_xor(32)
      bf16x8 pfr[4];
#pragma unroll
      for (int t = 0; t < 4; ++t) {
        const int ks = t >> 1, eb = (t & 1) * 8;
        unsigned we0 = pk2(st[ks][eb + 0], st[ks][eb + 1]);
        unsigned we1 = pk2(st[ks][eb + 2], st[ks][eb + 3]);
        unsigned wo0 = pk2(st[ks][eb + 4], st[ks][eb + 5]);
        unsigned wo1 = pk2(st[ks][eb + 6], st[ks][eb + 7]);
        unsigned s0 = hi ? we0 : wo0;
        unsigned s1 = hi ? we1 : wo1;
        unsigned r0 = __shfl_xor(s0, 32, 64);
        unsigned r1 = __shfl_xor(s1, 32, 64);
        union { unsigned u[4]; bf16x8 v; } pf;
        pf.u[0] = hi ? r0 : we0;
        pf.u[1] = hi ? r1 : we1;
        pf.u[2] = hi ? wo0 : r0;
        pf.u[3] = hi ? wo1 : r1;
        pfr[t] = pf.v;
      }

      // O^T[d][q] += V^T[d][kv] * P^T[kv][q]
      __builtin_amdgcn_s_setprio(1);
#pragma unroll
      for (int t = 0; t < 4; ++t) {
#pragma unroll
        for (int ds = 0; ds < 2; ++ds) {
          int d = ds * 32 + c32;
          bf16x8 vf = *(const bf16x8*)&vb[d * 64 + (((2 * t + hi) ^ (d & 7)) * 8)];
          o[ds] = __builtin_amdgcn_mfma_f32_32x32x16_bf16(vf, pfr[t], o[ds], 0, 0, 0);
        }
      }
      __builtin_amdgcn_s_setprio(0);
    }

    asm volatile("s_waitcnt vmcnt(0)" ::: "memory");
    __syncthreads();
    cur ^= 1;
  }

  // epilogue: O[q][d] = O^T[d][q] / l_r ; d = 8*rg + 4*hi + 32*ds + i
  const float inv = 1.0f / l_r;
  bf16* orow = aout + (size_t)(b * 2048 + myq) * 1024 + h * 64;
#pragma unroll
  for (int ds = 0; ds < 2; ++ds)
#pragma unroll
    for (int rg = 0; rg < 4; ++rg) {
      bf16x4 pk;
#pragma unroll
      for (int i = 0; i < 4; ++i) pk[i] = (bf16)(o[ds][rg * 4 + i] * inv);
      *(bf16x4*)&orow[ds * 32 + rg * 8 + hi * 4] = pk;
    }
}

// ---------------- launch ----------------
extern "C" void kernel_launch(void* const* d_in, const int* in_sizes, int n_in,
                              void* d_out, int out_size, void* d_ws, size_t ws_size,
                              hipStream_t stream) {
  const float* x    = (const float*)d_in[0];
  const float* Wqkv = (const float*)d_in[1];
  const float* bqkv = (const float*)d_in[2];
  const float* Wo   = (const float*)d_in[3];
  const float* bo   = (const float*)d_in[4];
  float* out = (float*)d_out;

  char* ws = (char*)d_ws;
  bf16* xb   = (bf16*)(ws);                  // 16 MB   [8192][1024]
  bf16* wqt  = (bf16*)(ws + 16777216);       // 6 MB    [3072][1024]
  bf16* wot  = (bf16*)(ws + 23068672);       // 2 MB    [1024][1024]
  bf16* qkb  = (bf16*)(ws + 25165824);       // 32 MB   [8192][2048]  (Q | K)
  bf16* vtb  = (bf16*)(ws + 58720256);       // 16 MB   [64 bh][64 d][2048 s]
  bf16* aob  = (bf16*)(ws + 75497472);       // 16 MB   [8192][1024]

  f32_to_bf16_k<<<dim3(4096), dim3(256), 0, stream>>>(x, xb);
  transpose_to_bf16_k<<<dim3(48, 16), dim3(256), 0, stream>>>(Wqkv, wqt, 1024, 3072);
  transpose_to_bf16_k<<<dim3(16, 16), dim3(256), 0, stream>>>(Wo, wot, 1024, 1024);
  gemm_bt<0><<<dim3(24, 64), dim3(256), 0, stream>>>(xb, wqt, bqkv, nullptr, qkb, vtb,
                                                     8192, 3072, 1024);
  attn_k<<<dim3(1024), dim3(256), 0, stream>>>(qkb, vtb, aob);
  gemm_bt<1><<<dim3(8, 64), dim3(256), 0, stream>>>(aob, wot, bo, out, nullptr, nullptr,
                                                    8192, 1024, 1024);
}

// Round 4
// 218.831 us; speedup vs baseline: 1.5556x; 1.0509x over previous
//
#include <hip/hip_runtime.h>
#include <hip/hip_bf16.h>
#include <stdint.h>

typedef __bf16 bf16;
typedef __bf16 bf16x8 __attribute__((ext_vector_type(8)));
typedef __bf16 bf16x4 __attribute__((ext_vector_type(4)));
typedef float  f32x4  __attribute__((ext_vector_type(4)));
typedef float  f32x16 __attribute__((ext_vector_type(16)));

// async global->LDS, 16B per lane; LDS dest = wave-uniform base + lane*16
__device__ __forceinline__ void load_lds16(const void* g, void* l) {
  __builtin_amdgcn_global_load_lds((const __attribute__((address_space(1))) void*)g,
                                   (__attribute__((address_space(3))) void*)l, 16, 0, 0);
}

__device__ __forceinline__ unsigned pk2(float a, float b) {
  union { bf16 h[2]; unsigned u; } t;
  t.h[0] = (bf16)a; t.h[1] = (bf16)b;
  return t.u;
}

// ---------------- convert x: f32 -> bf16, 8 elems/thread ----------------
__global__ __launch_bounds__(256) void f32_to_bf16_k(const float* __restrict__ in,
                                                     bf16* __restrict__ out) {
  int i = (blockIdx.x * 256 + threadIdx.x) * 8;
  float4 a = *(const float4*)(in + i);
  float4 b = *(const float4*)(in + i + 4);
  bf16x8 o;
  o[0] = (bf16)a.x; o[1] = (bf16)a.y; o[2] = (bf16)a.z; o[3] = (bf16)a.w;
  o[4] = (bf16)b.x; o[5] = (bf16)b.y; o[6] = (bf16)b.z; o[7] = (bf16)b.w;
  *(bf16x8*)(out + i) = o;
}

// ------------- transpose + convert: W[K][N] f32 -> WT[N][K] bf16 -------------
__global__ __launch_bounds__(256) void transpose_to_bf16_k(const float* __restrict__ in,
                                                           bf16* __restrict__ out,
                                                           int K, int N) {
  __shared__ __align__(16) bf16 tile[64 * 72];
  int n0 = blockIdx.x * 64, k0 = blockIdx.y * 64;
  int t = threadIdx.x;
  int r = t >> 2, cq = (t & 3) * 16;
  const float* src = in + (size_t)(k0 + r) * N + n0 + cq;
#pragma unroll
  for (int j = 0; j < 16; j += 4) {
    float4 v = *(const float4*)(src + j);
    tile[r * 72 + cq + j + 0] = (bf16)v.x;
    tile[r * 72 + cq + j + 1] = (bf16)v.y;
    tile[r * 72 + cq + j + 2] = (bf16)v.z;
    tile[r * 72 + cq + j + 3] = (bf16)v.w;
  }
  __syncthreads();
  bf16x8 r0, r1;
#pragma unroll
  for (int j = 0; j < 8; ++j) r0[j] = tile[(cq + j) * 72 + r];
#pragma unroll
  for (int j = 0; j < 8; ++j) r1[j] = tile[(cq + 8 + j) * 72 + r];
  bf16* dst = out + (size_t)(n0 + r) * K + k0 + cq;
  *(bf16x8*)(dst) = r0;
  *(bf16x8*)(dst + 8) = r1;
}

// ---------------- GEMM: C[M][N] = A[M][K] * BT[N][K]^T + bias ----------------
template <int EPI>
__global__ __launch_bounds__(256) void gemm_bt(const bf16* __restrict__ A,
                                               const bf16* __restrict__ BT,
                                               const float* __restrict__ bias,
                                               float* __restrict__ Cf,
                                               bf16* __restrict__ qk,
                                               bf16* __restrict__ vt,
                                               int M, int N, int K) {
  __shared__ __align__(16) bf16 As[128 * 32];
  __shared__ __align__(16) bf16 Bs[128 * 32];
  const int tid = threadIdx.x;
  const int w = tid >> 6, l = tid & 63;
  const int g = l >> 4, c = l & 15;
  const int wm = w >> 1, wn = w & 1;
  const int brow = blockIdx.y * 128;
  const int bcol = blockIdx.x * 128;
  const int lr = l >> 2;
  const int lk = (l & 3) * 8;

  f32x4 acc[4][4];
#pragma unroll
  for (int m = 0; m < 4; ++m)
#pragma unroll
    for (int n = 0; n < 4; ++n) acc[m][n] = f32x4{0.f, 0.f, 0.f, 0.f};

  const int nkt = K >> 5;
  for (int kt = 0; kt < nkt; ++kt) {
    if (kt) __syncthreads();
    const int k0 = kt * 32;
#pragma unroll
    for (int i = 0; i < 2; ++i) {
      int row = (w * 2 + i) * 16 + lr;
      load_lds16(A + (size_t)(brow + row) * K + k0 + lk, &As[(w * 2 + i) * 512]);
      load_lds16(BT + (size_t)(bcol + row) * K + k0 + lk, &Bs[(w * 2 + i) * 512]);
    }
    asm volatile("s_waitcnt vmcnt(0)" ::: "memory");
    __syncthreads();

    bf16x8 af[4], bfr[4];
#pragma unroll
    for (int m = 0; m < 4; ++m) af[m] = *(const bf16x8*)&As[(wm * 64 + m * 16 + c) * 32 + g * 8];
#pragma unroll
    for (int n = 0; n < 4; ++n) bfr[n] = *(const bf16x8*)&Bs[(wn * 64 + n * 16 + c) * 32 + g * 8];
#pragma unroll
    for (int m = 0; m < 4; ++m)
#pragma unroll
      for (int n = 0; n < 4; ++n)
        acc[m][n] = __builtin_amdgcn_mfma_f32_16x16x32_bf16(af[m], bfr[n], acc[m][n], 0, 0, 0);
  }

#pragma unroll
  for (int m = 0; m < 4; ++m) {
    int row_l = wm * 64 + m * 16 + g * 4;
#pragma unroll
    for (int n = 0; n < 4; ++n) {
      int col = bcol + wn * 64 + n * 16 + c;
      float bv = bias[col];
      if (EPI == 0) {
        if (bcol < 2048) {
#pragma unroll
          for (int r = 0; r < 4; ++r) {
            int row = brow + row_l + r;
            qk[(size_t)row * 2048 + col] = (bf16)(acc[m][n][r] + bv);
          }
        } else {
          int hh = (col - 2048) >> 6, dd = (col - 2048) & 63;
          int row0 = brow + row_l;
          int bb = row0 >> 11, ss = row0 & 2047;
          bf16x4 pk;
#pragma unroll
          for (int r = 0; r < 4; ++r) pk[r] = (bf16)(acc[m][n][r] + bv);
          *(bf16x4*)&vt[((size_t)(bb * 16 + hh) * 64 + dd) * 2048 + ss] = pk;
        }
      } else {
#pragma unroll
        for (int r = 0; r < 4; ++r) {
          int row = brow + row_l + r;
          Cf[(size_t)row * N + col] = acc[m][n][r] + bv;
        }
      }
    }
  }
}

// ---------------- flash attention v3 ----------------
// 512 blocks (2/CU, all resident), each processes TWO (bh,qblk) items:
// qblk = 15-pair then pair  -> 34 kv-tiles per block, perfectly uniform.
// Per item: 4 waves x 32 q rows; swapped-QK^T in-register softmax in exp2
// domain; tree reductions; defer-max (THR=8); double-buffered K/V^T LDS.
__global__ __launch_bounds__(256) void attn_k(const bf16* __restrict__ qkbuf,
                                              const bf16* __restrict__ vtbuf,
                                              bf16* __restrict__ aout) {
  __shared__ __align__(16) bf16 Ks[2][64 * 64];
  __shared__ __align__(16) bf16 Vs[2][64 * 64];

  const int tid = threadIdx.x;
  const int w = tid >> 6, l = tid & 63;
  const int c32 = l & 31, hi = l >> 5;

  // bid -> (xcd, bh, pair): each XCD owns bh [8x, 8x+8) -> K+V L2-fit
  const int bid = blockIdx.x;
  const int xcd = bid & 7;
  const int idx = bid >> 3;            // 0..63
  const int bh = xcd * 8 + (idx >> 3);
  const int pair = idx & 7;
  const int b = bh >> 4, h = bh & 15;

  const bf16* ksrc = qkbuf + (size_t)(b * 2048) * 2048 + 1024 + h * 64;  // K rows
  const bf16* vsrc = vtbuf + (size_t)(bh * 64) * 2048;                   // V^T rows
  // Q pre-scale folds softmax 1/sqrt(64) AND log2(e): scores in exp2 domain.
  const float QSCALE = 0.125f * 1.4426950408889634f;

#pragma unroll 1
  for (int item = 0; item < 2; ++item) {
    const int qblk = item == 0 ? 15 - pair : pair;
    const int q0 = qblk * 128;
    const int nt = 2 * qblk + 2;
    const int qw = q0 + w * 32;
    const int myq = qw + c32;

    // Q B-fragments: lane holds col q=myq, k(d) = 16t + hi*8 + j
    const size_t qoff = (size_t)(b * 2048 + myq) * 2048 + h * 64;
    bf16x8 qf[4];
#pragma unroll
    for (int t = 0; t < 4; ++t) {
      bf16x8 v = *(const bf16x8*)&qkbuf[qoff + t * 16 + hi * 8];
#pragma unroll
      for (int j = 0; j < 8; ++j) v[j] = (bf16)((float)v[j] * QSCALE);
      qf[t] = v;
    }

    float m_r = -1e30f, l_r = 0.f;
    f32x16 o[2];
    o[0] = (f32x16)(0.f); o[1] = (f32x16)(0.f);

    // prologue: stage tile 0 into buf 0 (prior item's waves all passed its
    // last barrier before this point, so LDS reuse is safe)
    {
      const int r = w * 16 + (l >> 3);
#pragma unroll
      for (int i = 0; i < 2; ++i) {
        int rr = r + i * 8;
        load_lds16(ksrc + (size_t)rr * 2048 + ((l & 7) ^ (rr & 7)) * 8, &Ks[0][(w * 16 + i * 8) * 64]);
        load_lds16(vsrc + (size_t)rr * 2048 + ((l & 7) ^ (rr & 7)) * 8, &Vs[0][(w * 16 + i * 8) * 64]);
      }
    }
    asm volatile("s_waitcnt vmcnt(0)" ::: "memory");
    __syncthreads();

    int cur = 0;
    for (int kt = 0; kt < nt; ++kt) {
      const int kv0 = kt * 64;

      // stage next tile into the other buffer
      if (kt + 1 < nt) {
        const int kvn = (kt + 1) * 64;
        const int r = w * 16 + (l >> 3);
#pragma unroll
        for (int i = 0; i < 2; ++i) {
          int rr = r + i * 8;
          load_lds16(ksrc + (size_t)(kvn + rr) * 2048 + ((l & 7) ^ (rr & 7)) * 8,
                     &Ks[cur ^ 1][(w * 16 + i * 8) * 64]);
          load_lds16(vsrc + (size_t)rr * 2048 + kvn + ((l & 7) ^ (rr & 7)) * 8,
                     &Vs[cur ^ 1][(w * 16 + i * 8) * 64]);
        }
      }

      if (kv0 <= qw + 31) {  // skip tiles fully above this wave's diagonal
        const bf16* kb = &Ks[cur][0];
        const bf16* vb = &Vs[cur][0];

        // S^T[kv][q] over d: 2 kv-subtiles x 4 ksteps
        f32x16 st[2];
        st[0] = (f32x16)(0.f); st[1] = (f32x16)(0.f);
        __builtin_amdgcn_s_setprio(1);
#pragma unroll
        for (int t = 0; t < 4; ++t) {
#pragma unroll
          for (int ks = 0; ks < 2; ++ks) {
            int kv = ks * 32 + c32;
            bf16x8 kf = *(const bf16x8*)&kb[kv * 64 + (((2 * t + hi) ^ (kv & 7)) * 8)];
            st[ks] = __builtin_amdgcn_mfma_f32_32x32x16_bf16(kf, qf[t], st[ks], 0, 0, 0);
          }
        }
        __builtin_amdgcn_s_setprio(0);

        // causal mask when tile reaches the wave's MIN q row
        if (kv0 + 63 > qw) {
#pragma unroll
          for (int ks = 0; ks < 2; ++ks)
#pragma unroll
            for (int r = 0; r < 16; ++r) {
              int kvidx = kv0 + ks * 32 + (r & 3) + 8 * (r >> 2) + 4 * hi;
              if (kvidx > myq) st[ks][r] = -1e30f;
            }
        }

        // tree max over 32 regs (depth ~5, max3-fusable) + 1 shfl
        float t0[8];
#pragma unroll
        for (int i = 0; i < 8; ++i)
          t0[i] = fmaxf(fmaxf(st[0][i], st[0][i + 8]), fmaxf(st[1][i], st[1][i + 8]));
        float mx = fmaxf(fmaxf(fmaxf(t0[0], t0[1]), fmaxf(t0[2], t0[3])),
                         fmaxf(fmaxf(t0[4], t0[5]), fmaxf(t0[6], t0[7])));
        mx = fmaxf(mx, __shfl_xor(mx, 32, 64));

        // defer-max: only rescale when some lane's max grew past THR=8
        if (__any(mx > m_r + 8.0f)) {
          float mn = fmaxf(m_r, mx);
          float al = exp2f(m_r - mn);
          m_r = mn;
          l_r *= al;
#pragma unroll
          for (int ds = 0; ds < 2; ++ds)
#pragma unroll
            for (int r = 0; r < 16; ++r) o[ds][r] *= al;
        }

        // P = exp2(S - m), sum in 4 ILP chains
        float s0 = 0.f, s1 = 0.f, s2 = 0.f, s3 = 0.f;
#pragma unroll
        for (int ks = 0; ks < 2; ++ks)
#pragma unroll
          for (int r = 0; r < 16; r += 4) {
            float p0 = exp2f(st[ks][r + 0] - m_r);
            float p1 = exp2f(st[ks][r + 1] - m_r);
            float p2 = exp2f(st[ks][r + 2] - m_r);
            float p3 = exp2f(st[ks][r + 3] - m_r);
            st[ks][r + 0] = p0; st[ks][r + 1] = p1;
            st[ks][r + 2] = p2; st[ks][r + 3] = p3;
            s0 += p0; s1 += p1; s2 += p2; s3 += p3;
          }
        float ps = (s0 + s1) + (s2 + s3);
        ps += __shfl_xor(ps, 32, 64);
        l_r += ps;

        // P -> bf16 B-operand fragments: per kstep, 4 packs + 2 shfl_xor(32)
        bf16x8 pfr[4];
#pragma unroll
        for (int t = 0; t < 4; ++t) {
          const int ks = t >> 1, eb = (t & 1) * 8;
          unsigned we0 = pk2(st[ks][eb + 0], st[ks][eb + 1]);
          unsigned we1 = pk2(st[ks][eb + 2], st[ks][eb + 3]);
          unsigned wo0 = pk2(st[ks][eb + 4], st[ks][eb + 5]);
          unsigned wo1 = pk2(st[ks][eb + 6], st[ks][eb + 7]);
          unsigned v0 = hi ? we0 : wo0;
          unsigned v1 = hi ? we1 : wo1;
          unsigned r0 = __shfl_xor(v0, 32, 64);
          unsigned r1 = __shfl_xor(v1, 32, 64);
          union { unsigned u[4]; bf16x8 v; } pf;
          pf.u[0] = hi ? r0 : we0;
          pf.u[1] = hi ? r1 : we1;
          pf.u[2] = hi ? wo0 : r0;
          pf.u[3] = hi ? wo1 : r1;
          pfr[t] = pf.v;
        }

        // O^T[d][q] += V^T[d][kv] * P^T[kv][q]
        __builtin_amdgcn_s_setprio(1);
#pragma unroll
        for (int t = 0; t < 4; ++t) {
#pragma unroll
          for (int ds = 0; ds < 2; ++ds) {
            int d = ds * 32 + c32;
            bf16x8 vf = *(const bf16x8*)&vb[d * 64 + (((2 * t + hi) ^ (d & 7)) * 8)];
            o[ds] = __builtin_amdgcn_mfma_f32_32x32x16_bf16(vf, pfr[t], o[ds], 0, 0, 0);
          }
        }
        __builtin_amdgcn_s_setprio(0);
      }

      asm volatile("s_waitcnt vmcnt(0)" ::: "memory");
      __syncthreads();
      cur ^= 1;
    }

    // epilogue: O[q][d] = O^T[d][q] / l_r ; d = 8*rg + 4*hi + 32*ds + i
    const float inv = 1.0f / l_r;
    bf16* orow = aout + (size_t)(b * 2048 + myq) * 1024 + h * 64;
#pragma unroll
    for (int ds = 0; ds < 2; ++ds)
#pragma unroll
      for (int rg = 0; rg < 4; ++rg) {
        bf16x4 pk;
#pragma unroll
        for (int i = 0; i < 4; ++i) pk[i] = (bf16)(o[ds][rg * 4 + i] * inv);
        *(bf16x4*)&orow[ds * 32 + rg * 8 + hi * 4] = pk;
      }
  }
}

// ---------------- launch ----------------
extern "C" void kernel_launch(void* const* d_in, const int* in_sizes, int n_in,
                              void* d_out, int out_size, void* d_ws, size_t ws_size,
                              hipStream_t stream) {
  const float* x    = (const float*)d_in[0];
  const float* Wqkv = (const float*)d_in[1];
  const float* bqkv = (const float*)d_in[2];
  const float* Wo   = (const float*)d_in[3];
  const float* bo   = (const float*)d_in[4];
  float* out = (float*)d_out;

  char* ws = (char*)d_ws;
  bf16* xb   = (bf16*)(ws);                  // 16 MB   [8192][1024]
  bf16* wqt  = (bf16*)(ws + 16777216);       // 6 MB    [3072][1024]
  bf16* wot  = (bf16*)(ws + 23068672);       // 2 MB    [1024][1024]
  bf16* qkb  = (bf16*)(ws + 25165824);       // 32 MB   [8192][2048]  (Q | K)
  bf16* vtb  = (bf16*)(ws + 58720256);       // 16 MB   [64 bh][64 d][2048 s]
  bf16* aob  = (bf16*)(ws + 75497472);       // 16 MB   [8192][1024]

  f32_to_bf16_k<<<dim3(4096), dim3(256), 0, stream>>>(x, xb);
  transpose_to_bf16_k<<<dim3(48, 16), dim3(256), 0, stream>>>(Wqkv, wqt, 1024, 3072);
  transpose_to_bf16_k<<<dim3(16, 16), dim3(256), 0, stream>>>(Wo, wot, 1024, 1024);
  gemm_bt<0><<<dim3(24, 64), dim3(256), 0, stream>>>(xb, wqt, bqkv, nullptr, qkb, vtb,
                                                     8192, 3072, 1024);
  attn_k<<<dim3(512), dim3(256), 0, stream>>>(qkb, vtb, aob);
  gemm_bt<1><<<dim3(8, 64), dim3(256), 0, stream>>>(aob, wot, bo, out, nullptr, nullptr,
                                                    8192, 1024, 1024);
}